// Round 7
// baseline (105.179 us; speedup 1.0000x reference)
//
#include <hip/hip_runtime.h>
#include <hip/hip_bf16.h>

#define NN 4096
#define DD 512
#define NKT 16                      // DD/32 K-steps

// ---- fused7: 128x128 block tile, 2 waves (each 128x64), mfma 32x32x16 ----
#define TILES 32
#define TRI (TILES*(TILES+1)/2)     // 528
#define NBLK (TILES*TILES + 2*TRI)  // 2080

#define BM 128                      // fallback geometry
#define BK 32
#define LDP 40

typedef __attribute__((ext_vector_type(8)))  short short8v;
typedef __attribute__((ext_vector_type(4)))  short short4v;
typedef __attribute__((ext_vector_type(4)))  float f32x4;
typedef __attribute__((ext_vector_type(16))) float f32x16;

static __device__ __forceinline__ short f2bf(float f) {
    union { float f; unsigned u; } a; a.f = f;
    unsigned r = a.u + 0x7FFFu + ((a.u >> 16) & 1u);
    return (short)(r >> 16);
}

static __device__ __forceinline__ void stage16(const void* g, void* l) {
    __builtin_amdgcn_global_load_lds(
        (const __attribute__((address_space(1))) unsigned int*)g,
        (__attribute__((address_space(3))) unsigned int*)l, 16, 0, 0);
}

static __device__ __forceinline__ void decode_tile(int bid, int& p, int& ti, int& tj, float& w) {
    w = 1.f;
    if (bid < TILES * TILES) {
        p = 2; ti = bid >> 5; tj = bid & (TILES - 1);
    } else {
        int u = bid - TILES * TILES;
        p = 0;
        if (u >= TRI) { p = 1; u -= TRI; }
        int a = 0;
        while (u >= TILES - a) { u -= TILES - a; ++a; }
        ti = a; tj = a + u;
        if (ti != tj) w = 2.f;
    }
}

// ---------- prep: fp32 -> bf16 ws + row norms ----------
__global__ void prep_kernel(const float* __restrict__ x, const float* __restrict__ y,
                            ushort* __restrict__ bx, ushort* __restrict__ by,
                            float* __restrict__ nx, float* __restrict__ ny) {
    int wid  = (blockIdx.x * blockDim.x + threadIdx.x) >> 6;
    int lane = threadIdx.x & 63;
    bool isx = wid < NN;
    const float* src = isx ? x : y;
    ushort* dst = isx ? bx : by;
    int row = wid & (NN - 1);
    const float4* p = (const float4*)(src + (size_t)row * DD);
    float s = 0.f;
    #pragma unroll
    for (int i = 0; i < 2; ++i) {
        float4 v = p[lane + 64 * i];
        s += v.x * v.x + v.y * v.y + v.z * v.z + v.w * v.w;
        short4v h = { f2bf(v.x), f2bf(v.y), f2bf(v.z), f2bf(v.w) };
        *(short4v*)(dst + (size_t)row * DD + 4 * (lane + 64 * i)) = h;
    }
    #pragma unroll
    for (int off = 32; off > 0; off >>= 1) s += __shfl_down(s, off);
    if (lane == 0) (isx ? nx : ny)[row] = s;
}

// ---------- fused7 ----------
__global__ void __launch_bounds__(128)
fused7_kernel(const ushort* __restrict__ bx, const ushort* __restrict__ by,
              const float* __restrict__ nx, const float* __restrict__ ny,
              float* __restrict__ out) {
    __shared__ __align__(16) ushort As0[4096];   // buf0: [128 rows][32 k] swizzled
    __shared__ __align__(16) ushort As1[4096];   // buf1
    __shared__ float wsum[2];

    int p, ti, tj; float w;
    decode_tile(blockIdx.x, p, ti, tj, w);

    const ushort* PB = (p == 1) ? by : bx;
    const ushort* QB = (p == 0) ? bx : by;
    const float*  NA = (p == 1) ? ny : nx;
    const float*  NB = (p == 0) ? nx : ny;

    const int t    = threadIdx.x;
    const int lane = t & 63;
    const int wv   = t >> 6;          // 0..1 -> 64-col band
    const int r5   = lane & 31;
    const int kh   = lane >> 5;       // 0/1 -> k-octet within a k-half
    const int rsw  = (lane >> 1) & 3; // read-swizzle term  = (row>>1)&3

    const ushort* Ag = PB + (size_t)ti * 128 * DD;
    const ushort* Bg = QB + (size_t)tj * 128 * DD;

    // staging geometry (round-3 verified involution: pos = c ^ ((row>>1)&3))
    const int srow = lane >> 2;                              // 16 rows x 4 chunks
    const int sc   = ((lane & 3) ^ ((lane >> 3) & 3)) * 8;   // inverse-swz src chunk

    // B column base: col = wv*64 + ni*32 + r5, k-octet kh
    const ushort* bcol = Bg + (size_t)(wv * 64 + r5) * DD + (kh << 3);

    f32x16 acc[4][2];
    #pragma unroll
    for (int mi = 0; mi < 4; ++mi)
        #pragma unroll
        for (int ni = 0; ni < 2; ++ni)
            #pragma unroll
            for (int r = 0; r < 16; ++r)
                acc[mi][ni][r] = 0.f;

#define STAGE_A(kt, BUF) do {                                              \
        _Pragma("unroll")                                                  \
        for (int i_ = 0; i_ < 4; ++i_) {                                   \
            int seg_ = wv * 4 + i_;                                        \
            stage16(Ag + (size_t)(seg_ * 16 + srow) * DD + (kt) * 32 + sc, \
                    &BUF[seg_ * 512]);                                     \
        }                                                                  \
    } while (0)

#define LDB(dst, kt) do {                                                  \
        dst[0][0] = *(const short8v*)(bcol + (kt) * 32);                   \
        dst[0][1] = *(const short8v*)(bcol + (size_t)32 * DD + (kt) * 32); \
        dst[1][0] = *(const short8v*)(bcol + (kt) * 32 + 16);              \
        dst[1][1] = *(const short8v*)(bcol + (size_t)32 * DD + (kt) * 32 + 16); \
    } while (0)

#define COMPUTE(BUF, bset) do {                                            \
        short8v af_[2][4];                                                 \
        _Pragma("unroll")                                                  \
        for (int kk_ = 0; kk_ < 2; ++kk_) {                                \
            int c_ = (kk_ * 2 + kh) ^ rsw;                                 \
            _Pragma("unroll")                                              \
            for (int mi_ = 0; mi_ < 4; ++mi_)                              \
                af_[kk_][mi_] = *(const short8v*)&BUF[(mi_ * 32 + r5) * 32 + c_ * 8]; \
        }                                                                  \
        __builtin_amdgcn_s_setprio(1);                                     \
        _Pragma("unroll")                                                  \
        for (int kk_ = 0; kk_ < 2; ++kk_)                                  \
            _Pragma("unroll")                                              \
            for (int mi_ = 0; mi_ < 4; ++mi_)                              \
                _Pragma("unroll")                                          \
                for (int ni_ = 0; ni_ < 2; ++ni_)                          \
                    acc[mi_][ni_] = __builtin_amdgcn_mfma_f32_32x32x16_bf16( \
                        af_[kk_][mi_], bset[kk_][ni_], acc[mi_][ni_], 0, 0, 0); \
        __builtin_amdgcn_s_setprio(0);                                     \
    } while (0)

    short8v bA[2][2], bB[2][2];   // [kk][ni], two k-step sets

    // prologue: A(0)->buf0, B(0)->bA, A(1)->buf1, B(1)->bB
    STAGE_A(0, As0); LDB(bA, 0);
    STAGE_A(1, As1); LDB(bB, 1);
    asm volatile("s_waitcnt vmcnt(8)" ::: "memory");   // A(0)+B(0) landed
    __builtin_amdgcn_s_barrier();

    #pragma unroll
    for (int kt2 = 0; kt2 < NKT; kt2 += 2) {
        COMPUTE(As0, bA);                                // k-step kt2
        __builtin_amdgcn_s_barrier();                    // all done reading buf0
        if (kt2 + 2 < NKT) {
            STAGE_A(kt2 + 2, As0); LDB(bA, kt2 + 2);
            asm volatile("s_waitcnt vmcnt(8)" ::: "memory");  // A(kt2+1)+B(kt2+1) landed
        } else {
            asm volatile("s_waitcnt vmcnt(0)" ::: "memory");
        }
        __builtin_amdgcn_s_barrier();

        COMPUTE(As1, bB);                                // k-step kt2+1
        __builtin_amdgcn_s_barrier();
        if (kt2 + 3 < NKT) {
            STAGE_A(kt2 + 3, As1); LDB(bB, kt2 + 3);
            asm volatile("s_waitcnt vmcnt(8)" ::: "memory");
        } else {
            asm volatile("s_waitcnt vmcnt(0)" ::: "memory");
        }
        __builtin_amdgcn_s_barrier();
    }

#undef STAGE_A
#undef LDB
#undef COMPUTE

    // ---- epilogue: C layout (32x32): col = lane&31, row = (r&3)+8*(r>>2)+4*(lane>>5) ----
    float nbv[2];
    #pragma unroll
    for (int ni = 0; ni < 2; ++ni)
        nbv[ni] = NB[tj * 128 + wv * 64 + ni * 32 + r5];

    float local = 0.f;
    #pragma unroll
    for (int mi = 0; mi < 4; ++mi) {
        #pragma unroll
        for (int g = 0; g < 4; ++g) {
            const int rowbase = mi * 32 + g * 8 + 4 * kh;      // + j (0..3)
            float4 na4 = *(const float4*)(&NA[ti * 128 + rowbase]);
            float nav[4] = { na4.x, na4.y, na4.z, na4.w };
            #pragma unroll
            for (int ni = 0; ni < 2; ++ni) {
                #pragma unroll
                for (int j = 0; j < 4; ++j) {
                    int r  = g * 4 + j;
                    int gr = ti * 128 + rowbase + j;
                    int gc = tj * 128 + wv * 64 + ni * 32 + r5;
                    float gv = acc[mi][ni][r];
                    float d2 = fmaxf(nav[j] + nbv[ni] - 2.f * gv, 0.f);
                    float e  = __expf(-d2);
                    if (p == 2) {
                        float diff = gv - ((gr == gc) ? 1.f : 0.f);
                        local += diff * diff - 2.f * e;
                    } else {
                        local += w * e;
                    }
                }
            }
        }
    }
    #pragma unroll
    for (int off = 32; off > 0; off >>= 1) local += __shfl_down(local, off);
    if (lane == 0) wsum[wv] = local;
    __syncthreads();
    if (t == 0)
        atomicAdd(out, (wsum[0] + wsum[1]) * (1.f / ((float)NN * (float)NN)));
}

// ---------- fallback path (round-1, used only if ws too small) ----------
__global__ void norms_kernel(const float* __restrict__ x, const float* __restrict__ y,
                             float* __restrict__ nx, float* __restrict__ ny) {
    int wid  = (blockIdx.x * blockDim.x + threadIdx.x) >> 6;
    int lane = threadIdx.x & 63;
    const float* src = (wid < NN) ? x : y;
    int row = wid & (NN - 1);
    const float4* p = (const float4*)(src + (size_t)row * DD);
    float s = 0.f;
    #pragma unroll
    for (int i = 0; i < 2; ++i) {
        float4 v = p[lane + 64 * i];
        s += v.x * v.x + v.y * v.y + v.z * v.z + v.w * v.w;
    }
    #pragma unroll
    for (int off = 32; off > 0; off >>= 1) s += __shfl_down(s, off);
    if (lane == 0) ((wid < NN) ? nx : ny)[row] = s;
}

__global__ void __launch_bounds__(256)
fused_kernel(const float* __restrict__ x, const float* __restrict__ y,
             const float* __restrict__ nx, const float* __restrict__ ny,
             float* __restrict__ out) {
    __shared__ __align__(16) short As[BM * LDP];
    __shared__ __align__(16) short Bs[BM * LDP];
    __shared__ float wsum[4];

    int p, ti, tj; float w;
    decode_tile(blockIdx.x, p, ti, tj, w);
    const float* P  = (p == 1) ? y  : x;
    const float* Q  = (p == 0) ? x  : y;
    const float* NA = (p == 1) ? ny : nx;
    const float* NB = (p == 0) ? nx : ny;

    const int t    = threadIdx.x;
    const int lane = t & 63;
    const int wvid = t >> 6;
    const int wm = wvid >> 1, wn = wvid & 1;

    f32x4 acc[4][4];
    #pragma unroll
    for (int m = 0; m < 4; ++m)
        #pragma unroll
        for (int n = 0; n < 4; ++n)
            acc[m][n] = (f32x4){0.f, 0.f, 0.f, 0.f};

    const int srow = t >> 3;
    const int scol = (t & 7) * 4;
    const size_t baseA = (size_t)(ti * BM) * DD;
    const size_t baseB = (size_t)(tj * BM) * DD;

    for (int kt = 0; kt < DD; kt += BK) {
        #pragma unroll
        for (int s = 0; s < 4; ++s) {
            int r = s * 32 + srow;
            float4 va = *(const float4*)(P + baseA + (size_t)r * DD + kt + scol);
            float4 vb = *(const float4*)(Q + baseB + (size_t)r * DD + kt + scol);
            short4v ha = { f2bf(va.x), f2bf(va.y), f2bf(va.z), f2bf(va.w) };
            short4v hb = { f2bf(vb.x), f2bf(vb.y), f2bf(vb.z), f2bf(vb.w) };
            *(short4v*)(&As[r * LDP + scol]) = ha;
            *(short4v*)(&Bs[r * LDP + scol]) = hb;
        }
        __syncthreads();

        short8v af[4], bfr[4];
        const int kc = (lane >> 4) * 8;
        #pragma unroll
        for (int m = 0; m < 4; ++m)
            af[m] = *(const short8v*)(&As[(wm * 64 + m * 16 + (lane & 15)) * LDP + kc]);
        #pragma unroll
        for (int n = 0; n < 4; ++n)
            bfr[n] = *(const short8v*)(&Bs[(wn * 64 + n * 16 + (lane & 15)) * LDP + kc]);
        #pragma unroll
        for (int m = 0; m < 4; ++m)
            #pragma unroll
            for (int n = 0; n < 4; ++n)
                acc[m][n] = __builtin_amdgcn_mfma_f32_16x16x32_bf16(af[m], bfr[n], acc[m][n], 0, 0, 0);
        __syncthreads();
    }

    float local = 0.f;
    #pragma unroll
    for (int m = 0; m < 4; ++m) {
        #pragma unroll
        for (int n = 0; n < 4; ++n) {
            #pragma unroll
            for (int r = 0; r < 4; ++r) {
                int row = wm * 64 + m * 16 + ((lane >> 4) << 2) + r;
                int col = wn * 64 + n * 16 + (lane & 15);
                int gr = ti * BM + row, gc = tj * BM + col;
                float g  = acc[m][n][r];
                float d2 = fmaxf(NA[gr] + NB[gc] - 2.f * g, 0.f);
                float e  = __expf(-d2);
                if (p == 2) {
                    float diff = g - ((gr == gc) ? 1.f : 0.f);
                    local += diff * diff - 2.f * e;
                } else {
                    local += w * e;
                }
            }
        }
    }
    #pragma unroll
    for (int off = 32; off > 0; off >>= 1) local += __shfl_down(local, off);
    if (lane == 0) wsum[wvid] = local;
    __syncthreads();
    if (t == 0) {
        float s = (wsum[0] + wsum[1]) + (wsum[2] + wsum[3]);
        atomicAdd(out, s * (1.f / ((float)NN * (float)NN)));
    }
}

extern "C" void kernel_launch(void* const* d_in, const int* in_sizes, int n_in,
                              void* d_out, int out_size, void* d_ws, size_t ws_size,
                              hipStream_t stream) {
    const float* x = (const float*)d_in[0];
    const float* y = (const float*)d_in[1];
    float* out = (float*)d_out;

    hipMemsetAsync(d_out, 0, sizeof(float), stream);

    const size_t need = (size_t)2 * NN * DD * sizeof(ushort) + (size_t)2 * NN * sizeof(float);
    if (ws_size >= need) {
        ushort* bx = (ushort*)d_ws;
        ushort* by = bx + (size_t)NN * DD;
        float*  nx = (float*)(by + (size_t)NN * DD);
        float*  ny = nx + NN;
        prep_kernel<<<dim3(2048), dim3(256), 0, stream>>>(x, y, bx, by, nx, ny);
        fused7_kernel<<<dim3(NBLK), dim3(128), 0, stream>>>(bx, by, nx, ny, out);
    } else {
        float* nx = (float*)d_ws;
        float* ny = nx + NN;
        norms_kernel<<<dim3(2048), dim3(256), 0, stream>>>(x, y, nx, ny);
        fused_kernel<<<dim3(NBLK), dim3(256), 0, stream>>>(x, y, nx, ny, out);
    }
}

// Round 8
// 74.855 us; speedup vs baseline: 1.4051x; 1.4051x over previous
//
#include <hip/hip_runtime.h>
#include <hip/hip_bf16.h>

#define NN 4096
#define DD 512

// ---- fused8: 128x128 tiles, 4 waves, BK=64, single buffer, swizzled ----
#define BK8 64
#define NKT8 8                      // DD/BK8
#define TILES 32
#define TRI (TILES*(TILES+1)/2)     // 528
#define NBLK (TILES*TILES + 2*TRI)  // 2080

#define BM 128                      // fallback geometry
#define BK 32
#define LDP 40

typedef __attribute__((ext_vector_type(8))) short short8v;
typedef __attribute__((ext_vector_type(4))) short short4v;
typedef __attribute__((ext_vector_type(4))) float f32x4;

static __device__ __forceinline__ short f2bf(float f) {
    union { float f; unsigned u; } a; a.f = f;
    unsigned r = a.u + 0x7FFFu + ((a.u >> 16) & 1u);
    return (short)(r >> 16);
}

static __device__ __forceinline__ void stage16(const void* g, void* l) {
    __builtin_amdgcn_global_load_lds(
        (const __attribute__((address_space(1))) unsigned int*)g,
        (__attribute__((address_space(3))) unsigned int*)l, 16, 0, 0);
}

static __device__ __forceinline__ void decode_tile(int bid, int& p, int& ti, int& tj, float& w) {
    w = 1.f;
    if (bid < TILES * TILES) {
        p = 2; ti = bid >> 5; tj = bid & (TILES - 1);
    } else {
        int u = bid - TILES * TILES;
        p = 0;
        if (u >= TRI) { p = 1; u -= TRI; }
        int a = 0;
        while (u >= TILES - a) { u -= TILES - a; ++a; }
        ti = a; tj = a + u;
        if (ti != tj) w = 2.f;
    }
}

// ---------- prep: fp32 -> bf16 ws + row norms ----------
__global__ void prep_kernel(const float* __restrict__ x, const float* __restrict__ y,
                            ushort* __restrict__ bx, ushort* __restrict__ by,
                            float* __restrict__ nx, float* __restrict__ ny) {
    int wid  = (blockIdx.x * blockDim.x + threadIdx.x) >> 6;
    int lane = threadIdx.x & 63;
    bool isx = wid < NN;
    const float* src = isx ? x : y;
    ushort* dst = isx ? bx : by;
    int row = wid & (NN - 1);
    const float4* p = (const float4*)(src + (size_t)row * DD);
    float s = 0.f;
    #pragma unroll
    for (int i = 0; i < 2; ++i) {
        float4 v = p[lane + 64 * i];
        s += v.x * v.x + v.y * v.y + v.z * v.z + v.w * v.w;
        short4v h = { f2bf(v.x), f2bf(v.y), f2bf(v.z), f2bf(v.w) };
        *(short4v*)(dst + (size_t)row * DD + 4 * (lane + 64 * i)) = h;
    }
    #pragma unroll
    for (int off = 32; off > 0; off >>= 1) s += __shfl_down(s, off);
    if (lane == 0) (isx ? nx : ny)[row] = s;
}

// ---------- fused8 ----------
// LDS layout per matrix: [128 rows][8 chunks of 16B], stored chunk-position
// pos = c ^ (row & 7)   (G4's documented 128B-row fix; involution).
// gload_lds dest is linear (base + lane*16B); source chunk is inverse-swizzled.
__global__ void __launch_bounds__(256)
fused8_kernel(const ushort* __restrict__ bx, const ushort* __restrict__ by,
              const float* __restrict__ nx, const float* __restrict__ ny,
              float* __restrict__ out) {
    __shared__ __align__(16) ushort As[128 * 64];   // 16 KiB
    __shared__ __align__(16) ushort Bs[128 * 64];   // 16 KiB
    __shared__ float wsum[4];

    int p, ti, tj; float w;
    decode_tile(blockIdx.x, p, ti, tj, w);

    const ushort* PB = (p == 1) ? by : bx;
    const ushort* QB = (p == 0) ? bx : by;
    const float*  NA = (p == 1) ? ny : nx;
    const float*  NB = (p == 0) ? nx : ny;

    const int t    = threadIdx.x;
    const int lane = t & 63;
    const int wv   = t >> 6;          // 0..3
    const int wm   = wv >> 1, wn = wv & 1;
    const int fr   = lane & 15;
    const int ch   = lane >> 4;       // 0..3 logical k-chunk base within kk

    const ushort* Ag = PB + (size_t)ti * 128 * DD;
    const ushort* Bg = QB + (size_t)tj * 128 * DD;

    // staging: issue i covers rows i*32 + wv*8 + (lane>>3), position lane&7.
    // LDS dst = i*4096B + wv*1024B + lane*16B (wave-uniform base + lane*16) ✓
    // source logical chunk c = pos ^ (row&7) = (lane&7) ^ ((lane>>3)&7)
    const int srow = (lane >> 3);                       // 0..7
    const int sc8  = ((lane & 7) ^ ((lane >> 3) & 7)) * 8;   // ushort offset

    f32x4 acc[4][4];
    #pragma unroll
    for (int m = 0; m < 4; ++m)
        #pragma unroll
        for (int n = 0; n < 4; ++n)
            acc[m][n] = (f32x4){0.f, 0.f, 0.f, 0.f};

#define STAGE8(kt) do {                                                        \
        _Pragma("unroll")                                                      \
        for (int i_ = 0; i_ < 4; ++i_) {                                       \
            int row_ = i_ * 32 + wv * 8 + srow;                                \
            stage16(Ag + (size_t)row_ * DD + (kt) * BK8 + sc8,                 \
                    &As[i_ * 2048 + wv * 512 + lane * 8]);                     \
            stage16(Bg + (size_t)row_ * DD + (kt) * BK8 + sc8,                 \
                    &Bs[i_ * 2048 + wv * 512 + lane * 8]);                     \
        }                                                                      \
    } while (0)

    // prologue
    STAGE8(0);
    __syncthreads();

    for (int kt = 0; kt < NKT8; ++kt) {
        // 1) read all 16 fragments of this K-tile (kk = 0,1)
        short8v af[2][4], bf[2][4];
        #pragma unroll
        for (int kk = 0; kk < 2; ++kk) {
            const int pa = ((kk * 4 + ch) ^ (fr & 7)) * 8;   // swizzled chunk offset
            #pragma unroll
            for (int m = 0; m < 4; ++m)
                af[kk][m] = *(const short8v*)&As[(wm * 64 + m * 16 + fr) * 64 + pa];
            #pragma unroll
            for (int n = 0; n < 4; ++n)
                bf[kk][n] = *(const short8v*)&Bs[(wn * 64 + n * 16 + fr) * 64 + pa];
        }
        __syncthreads();                 // all waves done reading the buffer

        // 2) issue next-tile staging (overlaps the MFMA cluster below)
        if (kt + 1 < NKT8) STAGE8(kt + 1);

        // 3) MFMA cluster
        #pragma unroll
        for (int kk = 0; kk < 2; ++kk)
            #pragma unroll
            for (int m = 0; m < 4; ++m)
                #pragma unroll
                for (int n = 0; n < 4; ++n)
                    acc[m][n] = __builtin_amdgcn_mfma_f32_16x16x32_bf16(
                        af[kk][m], bf[kk][n], acc[m][n], 0, 0, 0);

        // 4) drain (vmcnt inside syncthreads) + swap-free: single buffer
        __syncthreads();
    }
#undef STAGE8

    // ---- epilogue (identical to fused2's verified layout) ----
    float nbv[4];
    #pragma unroll
    for (int n = 0; n < 4; ++n)
        nbv[n] = NB[tj * 128 + wn * 64 + n * 16 + fr];
    const int rbase = ((lane >> 4) << 2);

    float local = 0.f;
    #pragma unroll
    for (int m = 0; m < 4; ++m) {
        float4 na4 = *(const float4*)(&NA[ti * 128 + wm * 64 + m * 16 + rbase]);
        float nav[4] = { na4.x, na4.y, na4.z, na4.w };
        #pragma unroll
        for (int n = 0; n < 4; ++n) {
            #pragma unroll
            for (int rr = 0; rr < 4; ++rr) {
                int gr = ti * 128 + wm * 64 + m * 16 + rbase + rr;
                int gc = tj * 128 + wn * 64 + n * 16 + fr;
                float g  = acc[m][n][rr];
                float d2 = fmaxf(nav[rr] + nbv[n] - 2.f * g, 0.f);
                float e  = __expf(-d2);
                if (p == 2) {
                    float diff = g - ((gr == gc) ? 1.f : 0.f);
                    local += diff * diff - 2.f * e;
                } else {
                    local += w * e;
                }
            }
        }
    }
    #pragma unroll
    for (int off = 32; off > 0; off >>= 1) local += __shfl_down(local, off);
    if (lane == 0) wsum[wv] = local;
    __syncthreads();
    if (t == 0) {
        float s = (wsum[0] + wsum[1]) + (wsum[2] + wsum[3]);
        atomicAdd(out, s * (1.f / ((float)NN * (float)NN)));
    }
}

// ---------- fallback path (round-1, used only if ws too small) ----------
__global__ void norms_kernel(const float* __restrict__ x, const float* __restrict__ y,
                             float* __restrict__ nx, float* __restrict__ ny) {
    int wid  = (blockIdx.x * blockDim.x + threadIdx.x) >> 6;
    int lane = threadIdx.x & 63;
    const float* src = (wid < NN) ? x : y;
    int row = wid & (NN - 1);
    const float4* p = (const float4*)(src + (size_t)row * DD);
    float s = 0.f;
    #pragma unroll
    for (int i = 0; i < 2; ++i) {
        float4 v = p[lane + 64 * i];
        s += v.x * v.x + v.y * v.y + v.z * v.z + v.w * v.w;
    }
    #pragma unroll
    for (int off = 32; off > 0; off >>= 1) s += __shfl_down(s, off);
    if (lane == 0) ((wid < NN) ? nx : ny)[row] = s;
}

__global__ void __launch_bounds__(256)
fused_kernel(const float* __restrict__ x, const float* __restrict__ y,
             const float* __restrict__ nx, const float* __restrict__ ny,
             float* __restrict__ out) {
    __shared__ __align__(16) short As[BM * LDP];
    __shared__ __align__(16) short Bs[BM * LDP];
    __shared__ float wsum[4];

    int p, ti, tj; float w;
    decode_tile(blockIdx.x, p, ti, tj, w);
    const float* P  = (p == 1) ? y  : x;
    const float* Q  = (p == 0) ? x  : y;
    const float* NA = (p == 1) ? ny : nx;
    const float* NB = (p == 0) ? nx : ny;

    const int t    = threadIdx.x;
    const int lane = t & 63;
    const int wvid = t >> 6;
    const int wm = wvid >> 1, wn = wvid & 1;

    f32x4 acc[4][4];
    #pragma unroll
    for (int m = 0; m < 4; ++m)
        #pragma unroll
        for (int n = 0; n < 4; ++n)
            acc[m][n] = (f32x4){0.f, 0.f, 0.f, 0.f};

    const int srow = t >> 3;
    const int scol = (t & 7) * 4;
    const size_t baseA = (size_t)(ti * BM) * DD;
    const size_t baseB = (size_t)(tj * BM) * DD;

    for (int kt = 0; kt < DD; kt += BK) {
        #pragma unroll
        for (int s = 0; s < 4; ++s) {
            int r = s * 32 + srow;
            float4 va = *(const float4*)(P + baseA + (size_t)r * DD + kt + scol);
            float4 vb = *(const float4*)(Q + baseB + (size_t)r * DD + kt + scol);
            short4v ha = { f2bf(va.x), f2bf(va.y), f2bf(va.z), f2bf(va.w) };
            short4v hb = { f2bf(vb.x), f2bf(vb.y), f2bf(vb.z), f2bf(vb.w) };
            *(short4v*)(&As[r * LDP + scol]) = ha;
            *(short4v*)(&Bs[r * LDP + scol]) = hb;
        }
        __syncthreads();

        short8v af[4], bfr[4];
        const int kc = (lane >> 4) * 8;
        #pragma unroll
        for (int m = 0; m < 4; ++m)
            af[m] = *(const short8v*)(&As[(wm * 64 + m * 16 + (lane & 15)) * LDP + kc]);
        #pragma unroll
        for (int n = 0; n < 4; ++n)
            bfr[n] = *(const short8v*)(&Bs[(wn * 64 + n * 16 + (lane & 15)) * LDP + kc]);
        #pragma unroll
        for (int m = 0; m < 4; ++m)
            #pragma unroll
            for (int n = 0; n < 4; ++n)
                acc[m][n] = __builtin_amdgcn_mfma_f32_16x16x32_bf16(af[m], bfr[n], acc[m][n], 0, 0, 0);
        __syncthreads();
    }

    float local = 0.f;
    #pragma unroll
    for (int m = 0; m < 4; ++m) {
        #pragma unroll
        for (int n = 0; n < 4; ++n) {
            #pragma unroll
            for (int r = 0; r < 4; ++r) {
                int row = wm * 64 + m * 16 + ((lane >> 4) << 2) + r;
                int col = wn * 64 + n * 16 + (lane & 15);
                int gr = ti * BM + row, gc = tj * BM + col;
                float g  = acc[m][n][r];
                float d2 = fmaxf(NA[gr] + NB[gc] - 2.f * g, 0.f);
                float e  = __expf(-d2);
                if (p == 2) {
                    float diff = g - ((gr == gc) ? 1.f : 0.f);
                    local += diff * diff - 2.f * e;
                } else {
                    local += w * e;
                }
            }
        }
    }
    #pragma unroll
    for (int off = 32; off > 0; off >>= 1) local += __shfl_down(local, off);
    if (lane == 0) wsum[wvid] = local;
    __syncthreads();
    if (t == 0) {
        float s = (wsum[0] + wsum[1]) + (wsum[2] + wsum[3]);
        atomicAdd(out, s * (1.f / ((float)NN * (float)NN)));
    }
}

extern "C" void kernel_launch(void* const* d_in, const int* in_sizes, int n_in,
                              void* d_out, int out_size, void* d_ws, size_t ws_size,
                              hipStream_t stream) {
    const float* x = (const float*)d_in[0];
    const float* y = (const float*)d_in[1];
    float* out = (float*)d_out;

    hipMemsetAsync(d_out, 0, sizeof(float), stream);

    const size_t need = (size_t)2 * NN * DD * sizeof(ushort) + (size_t)2 * NN * sizeof(float);
    if (ws_size >= need) {
        ushort* bx = (ushort*)d_ws;
        ushort* by = bx + (size_t)NN * DD;
        float*  nx = (float*)(by + (size_t)NN * DD);
        float*  ny = nx + NN;
        prep_kernel<<<dim3(2048), dim3(256), 0, stream>>>(x, y, bx, by, nx, ny);
        fused8_kernel<<<dim3(NBLK), dim3(256), 0, stream>>>(bx, by, nx, ny, out);
    } else {
        float* nx = (float*)d_ws;
        float* ny = nx + NN;
        norms_kernel<<<dim3(2048), dim3(256), 0, stream>>>(x, y, nx, ny);
        fused_kernel<<<dim3(NBLK), dim3(256), 0, stream>>>(x, y, nx, ny, out);
    }
}